// Round 6
// baseline (377.214 us; speedup 1.0000x reference)
//
#include <hip/hip_runtime.h>
#include <cstdint>
#include <cstddef>

#define B_DIM 16
#define N_DIM 2048
#define BN (B_DIM * N_DIM)          // 32768 rows per modality
#define QSCALE 0.18033688f          // 0.125 * log2(e): P = exp2(S')
#define PLANE ((size_t)BN * 64)     // elems per (jj,i) partial plane

typedef __attribute__((ext_vector_type(4))) float f32x4;
typedef __attribute__((ext_vector_type(16))) float f32x16;
typedef __attribute__((ext_vector_type(8))) __bf16 bf16x8;
typedef __attribute__((ext_vector_type(2))) unsigned int u32x2;

__device__ __forceinline__ unsigned short f2bf_rne(float f) {
    union { float f; unsigned int u; } v; v.f = f;
    unsigned int u = v.u;
    return (unsigned short)((u + 0x7fffu + ((u >> 16) & 1u)) >> 16);
}
__device__ __forceinline__ unsigned pk_rne(float a, float b) {
    return (unsigned)f2bf_rne(a) | ((unsigned)f2bf_rne(b) << 16);
}
// half_swap(a,b): res.x = {a.lo32, b.lo32}, res.y = {a.hi32, b.hi32}
__device__ __forceinline__ u32x2 half_swap(unsigned a, unsigned b) {
#if __has_builtin(__builtin_amdgcn_permlane32_swap)
    return __builtin_amdgcn_permlane32_swap(a, b, false, false);
#else
    unsigned pa = (unsigned)__shfl_xor((int)a, 32);
    unsigned pb = (unsigned)__shfl_xor((int)b, 32);
    bool hi = (threadIdx.x & 32) != 0;
    u32x2 r;
    r.x = hi ? pb : a;
    r.y = hi ? b : pa;
    return r;
#endif
}

// ---------------------------------------------------------------------------
// prep (MFMA): Q = (x@W)*QSCALE, K = x@W^T  (bf16 rows), Vt = x^T (bf16, [m][b][d][n])
// block = 256 thr, 128 x-rows; wave w owns rows 32w..32w+31   (unchanged, verified)
// ---------------------------------------------------------------------------
__global__ __launch_bounds__(256) void prep_kernel(
    const float* __restrict__ x0, const float* __restrict__ x1, const float* __restrict__ x2,
    const float* __restrict__ w0, const float* __restrict__ w1, const float* __restrict__ w2,
    unsigned short* __restrict__ Qbf, unsigned short* __restrict__ Kbf,
    unsigned short* __restrict__ Vt)
{
    __shared__ float Wf[64 * 64];
    __shared__ float xs[128 * 68];

    int m    = blockIdx.x >> 8;
    int tile = blockIdx.x & 255;
    int row0 = tile * 128;
    int b    = row0 >> 11;
    int n0   = row0 & 2047;
    const float* x = (m == 0) ? x0 : (m == 1) ? x1 : x2;
    const float* W = (m == 0) ? w0 : (m == 1) ? w1 : w2;
    int tid = threadIdx.x;

    #pragma unroll
    for (int v = 0; v < 4; ++v) {
        int i4 = v * 256 + tid;
        *(f32x4*)&Wf[i4 * 4] = *(const f32x4*)&W[i4 * 4];
    }
    #pragma unroll
    for (int v = 0; v < 8; ++v) {
        int i4 = v * 256 + tid;
        int r = i4 >> 4, c = (i4 & 15) * 4;
        *(f32x4*)&xs[r * 68 + c] = *(const f32x4*)&x[(size_t)row0 * 64 + i4 * 4];
    }
    __syncthreads();

    int lane = tid & 63, wave = tid >> 6, lq = lane & 31, h = lane >> 5;

    bf16x8 wq[2][4], wk[2][4];
    #pragma unroll
    for (int mf = 0; mf < 2; ++mf)
        #pragma unroll
        for (int kc = 0; kc < 4; ++kc) {
            int e  = mf * 32 + lq;
            int d0 = kc * 16 + h * 8;
            unsigned uq[4], uk[4];
            #pragma unroll
            for (int t = 0; t < 4; ++t) {
                int d = d0 + 2 * t;
                uq[t] = pk_rne(Wf[d * 64 + e] * QSCALE, Wf[(d + 1) * 64 + e] * QSCALE);
                uk[t] = pk_rne(Wf[e * 64 + d], Wf[e * 64 + d + 1]);
            }
            uint4 ua; ua.x = uq[0]; ua.y = uq[1]; ua.z = uq[2]; ua.w = uq[3];
            uint4 ub; ub.x = uk[0]; ub.y = uk[1]; ub.z = uk[2]; ub.w = uk[3];
            wq[mf][kc] = __builtin_bit_cast(bf16x8, ua);
            wk[mf][kc] = __builtin_bit_cast(bf16x8, ub);
        }

    bf16x8 xb[4];
    #pragma unroll
    for (int kc = 0; kc < 4; ++kc) {
        const float* xr = &xs[(wave * 32 + lq) * 68 + kc * 16 + h * 8];
        unsigned u[4];
        #pragma unroll
        for (int t = 0; t < 4; ++t) u[t] = pk_rne(xr[2 * t], xr[2 * t + 1]);
        uint4 ua; ua.x = u[0]; ua.y = u[1]; ua.z = u[2]; ua.w = u[3];
        xb[kc] = __builtin_bit_cast(bf16x8, ua);
    }

    f32x16 Qt[2], Kt[2];
    #pragma unroll
    for (int r = 0; r < 16; ++r) { Qt[0][r] = 0.f; Qt[1][r] = 0.f; Kt[0][r] = 0.f; Kt[1][r] = 0.f; }
    #pragma unroll
    for (int kc = 0; kc < 4; ++kc) {
        #pragma unroll
        for (int mf = 0; mf < 2; ++mf) {
            Qt[mf] = __builtin_amdgcn_mfma_f32_32x32x16_bf16(wq[mf][kc], xb[kc], Qt[mf], 0, 0, 0);
            Kt[mf] = __builtin_amdgcn_mfma_f32_32x32x16_bf16(wk[mf][kc], xb[kc], Kt[mf], 0, 0, 0);
        }
    }

    size_t rowidx = (size_t)m * BN + row0 + wave * 32 + lq;
    unsigned short* qdst = Qbf + rowidx * 64 + h * 32;
    unsigned short* kdst = Kbf + rowidx * 64 + h * 32;
    #pragma unroll
    for (int s = 0; s < 4; ++s) {
        unsigned q00 = pk_rne(Qt[0][4 * s], Qt[0][4 * s + 1]);
        unsigned q01 = pk_rne(Qt[0][4 * s + 2], Qt[0][4 * s + 3]);
        unsigned q10 = pk_rne(Qt[1][4 * s], Qt[1][4 * s + 1]);
        unsigned q11 = pk_rne(Qt[1][4 * s + 2], Qt[1][4 * s + 3]);
        u32x2 a = half_swap(q00, q10);
        u32x2 c = half_swap(q01, q11);
        uint4 w; w.x = a.x; w.y = c.x; w.z = a.y; w.w = c.y;
        *(uint4*)&qdst[s * 8] = w;

        unsigned k00 = pk_rne(Kt[0][4 * s], Kt[0][4 * s + 1]);
        unsigned k01 = pk_rne(Kt[0][4 * s + 2], Kt[0][4 * s + 3]);
        unsigned k10 = pk_rne(Kt[1][4 * s], Kt[1][4 * s + 1]);
        unsigned k11 = pk_rne(Kt[1][4 * s + 2], Kt[1][4 * s + 3]);
        u32x2 a2 = half_swap(k00, k10);
        u32x2 c2 = half_swap(k01, k11);
        uint4 w2; w2.x = a2.x; w2.y = c2.x; w2.z = a2.y; w2.w = c2.y;
        *(uint4*)&kdst[s * 8] = w2;
    }

    int d  = tid & 63;
    int ng = tid >> 6;
    unsigned short* vdst = Vt + ((size_t)(m * B_DIM + b) * 64 + d) * 2048 + n0 + ng * 32;
    #pragma unroll
    for (int s = 0; s < 4; ++s) {
        uint4 w;
        w.x = pk_rne(xs[(ng * 32 + 8 * s + 0) * 68 + d], xs[(ng * 32 + 8 * s + 1) * 68 + d]);
        w.y = pk_rne(xs[(ng * 32 + 8 * s + 2) * 68 + d], xs[(ng * 32 + 8 * s + 3) * 68 + d]);
        w.z = pk_rne(xs[(ng * 32 + 8 * s + 4) * 68 + d], xs[(ng * 32 + 8 * s + 5) * 68 + d]);
        w.w = pk_rne(xs[(ng * 32 + 8 * s + 6) * 68 + d], xs[(ng * 32 + 8 * s + 7) * 68 + d]);
        *(uint4*)&vdst[s * 8] = w;
    }
}

// ---------------------------------------------------------------------------
// attention: block = one (pair, b, 256-q tile); 4 waves x 64 q-rows each.
// NO LDS, NO BARRIERS: K/V fragments loaded global->register in A-operand
// lane layout (L1/L2 serve the 16 KB tiles; 4 waves/block reuse them).
// Waves run fully desynchronized -> MFMA/trans/VALU pipes overlap across waves.
// ---------------------------------------------------------------------------
__global__ __launch_bounds__(256, 3) void attn_kernel(
    const unsigned short* __restrict__ Qbf,
    const unsigned short* __restrict__ Kbf,
    const unsigned short* __restrict__ Vt,
    unsigned short* __restrict__ part)
{
    int blk = blockIdx.x;                    // 768 = 6 pairs * 16 b * 8 qt
    int qt  = blk & 7;
    int b   = (blk >> 3) & 15;
    int p   = blk >> 7;
    int i   = p >> 1, jj = p & 1;
    int j   = i + 1 + jj; if (j >= 3) j -= 3;
    int q0  = qt * 256;

    int tid = threadIdx.x, wave = tid >> 6, lane = tid & 63;
    int lq = lane & 31, h = lane >> 5;

    const unsigned short* Kg = Kbf + ((size_t)j * BN + b * N_DIM) * 64;
    const unsigned short* Vg = Vt + (size_t)(j * B_DIM + b) * 64 * 2048;

    // Q B-frags (block-constant): q = q0+64w+32qi+lq, k = 16kc+8h+..
    const unsigned short* Qg = Qbf + ((size_t)i * BN + b * N_DIM + q0 + wave * 64) * 64;
    bf16x8 qf[2][4];
    #pragma unroll
    for (int qi = 0; qi < 2; ++qi)
        #pragma unroll
        for (int kc = 0; kc < 4; ++kc)
            qf[qi][kc] = __builtin_bit_cast(bf16x8,
                *(const uint4*)&Qg[(qi * 32 + lq) * 64 + kc * 16 + h * 8]);

    // per-lane base offsets for K/V A-frag loads
    const unsigned short* kbase = Kg + (size_t)lq * 64 + h * 8;          // + kf*2048 + kc*16 + kt*4096
    const unsigned short* vbase = Vg + (size_t)lq * 2048 + h * 8;        // + df*65536 + kcpv*16 + kt*64

    f32x16 O[2][2];                          // [df][qi]
    #pragma unroll
    for (int r = 0; r < 16; ++r) { O[0][0][r] = 0.f; O[0][1][r] = 0.f; O[1][0][r] = 0.f; O[1][1][r] = 0.f; }
    float lsum[2] = {0.f, 0.f};

    for (int kt = 0; kt < 32; ++kt) {
        const unsigned short* kb = kbase + (size_t)kt * 4096;
        const unsigned short* vb = vbase + kt * 64;

        #pragma unroll
        for (int kf = 0; kf < 2; ++kf) {
            // K A-frags for this 32-key group, straight from global (L1/L2)
            bf16x8 kfr[4];
            #pragma unroll
            for (int kc = 0; kc < 4; ++kc)
                kfr[kc] = __builtin_bit_cast(bf16x8,
                    *(const uint4*)(kb + kf * 2048 + kc * 16));

            unsigned pkk[2][4][2];
            #pragma unroll
            for (int qi = 0; qi < 2; ++qi) {
                f32x16 st;
                #pragma unroll
                for (int r = 0; r < 16; ++r) st[r] = 0.f;
                #pragma unroll
                for (int kc = 0; kc < 4; ++kc)
                    st = __builtin_amdgcn_mfma_f32_32x32x16_bf16(kfr[kc], qf[qi][kc], st, 0, 0, 0);
                #pragma unroll
                for (int s = 0; s < 4; ++s) {
                    float e0 = __builtin_amdgcn_exp2f(st[4 * s + 0]);
                    float e1 = __builtin_amdgcn_exp2f(st[4 * s + 1]);
                    float e2 = __builtin_amdgcn_exp2f(st[4 * s + 2]);
                    float e3 = __builtin_amdgcn_exp2f(st[4 * s + 3]);
                    lsum[qi] += (e0 + e1) + (e2 + e3);
                    pkk[qi][s][0] = __builtin_amdgcn_perm(
                        __builtin_bit_cast(unsigned, e1), __builtin_bit_cast(unsigned, e0), 0x07060302u);
                    pkk[qi][s][1] = __builtin_amdgcn_perm(
                        __builtin_bit_cast(unsigned, e3), __builtin_bit_cast(unsigned, e2), 0x07060302u);
                }
            }

            #pragma unroll
            for (int c = 0; c < 2; ++c) {
                bf16x8 pf[2];
                #pragma unroll
                for (int qi = 0; qi < 2; ++qi) {
                    u32x2 rr0 = half_swap(pkk[qi][2 * c][0], pkk[qi][2 * c + 1][0]);
                    u32x2 rr1 = half_swap(pkk[qi][2 * c][1], pkk[qi][2 * c + 1][1]);
                    uint4 t; t.x = rr0.x; t.y = rr1.x; t.z = rr0.y; t.w = rr1.y;
                    pf[qi] = __builtin_bit_cast(bf16x8, t);
                }
                int kcpv = 2 * kf + c;
                #pragma unroll
                for (int df = 0; df < 2; ++df) {
                    // V^T A-frag straight from global: row d = df*32+lq
                    bf16x8 vfr = __builtin_bit_cast(bf16x8,
                        *(const uint4*)(vb + (size_t)df * 32 * 2048 + kcpv * 16));
                    O[df][0] = __builtin_amdgcn_mfma_f32_32x32x16_bf16(vfr, pf[0], O[df][0], 0, 0, 0);
                    O[df][1] = __builtin_amdgcn_mfma_f32_32x32x16_bf16(vfr, pf[1], O[df][1], 0, 0, 0);
                }
            }
        }
    }

    // epilogue: normalize, half-swap to row layout, store bf16 partial rows
    #pragma unroll
    for (int qi = 0; qi < 2; ++qi) {
        float l = lsum[qi];
        l += __shfl_xor(l, 32);
        float inv = 1.0f / l;
        #pragma unroll
        for (int r = 0; r < 16; ++r) { O[0][qi][r] *= inv; O[1][qi][r] *= inv; }

        unsigned short* dst = part + ((size_t)jj * 3 + i) * PLANE
            + (size_t)(b * N_DIM + q0 + wave * 64 + qi * 32 + lq) * 64 + h * 32;
        #pragma unroll
        for (int s = 0; s < 4; ++s) {
            unsigned t00 = pk_rne(O[0][qi][4 * s], O[0][qi][4 * s + 1]);
            unsigned t01 = pk_rne(O[0][qi][4 * s + 2], O[0][qi][4 * s + 3]);
            unsigned t10 = pk_rne(O[1][qi][4 * s], O[1][qi][4 * s + 1]);
            unsigned t11 = pk_rne(O[1][qi][4 * s + 2], O[1][qi][4 * s + 3]);
            u32x2 a = half_swap(t00, t10);
            u32x2 c = half_swap(t01, t11);
            uint4 w; w.x = a.x; w.y = c.x; w.z = a.y; w.w = c.y;
            *(uint4*)&dst[s * 8] = w;
        }
    }
}

// ---------------------------------------------------------------------------
// reduce: out = (1/3) * sum of 6 bf16 partial planes
// ---------------------------------------------------------------------------
__global__ __launch_bounds__(256) void reduce_kernel(
    const unsigned short* __restrict__ part, float* __restrict__ out)
{
    size_t e = ((size_t)blockIdx.x * 256 + threadIdx.x) * 4;
    float a0 = 0.f, a1 = 0.f, a2 = 0.f, a3 = 0.f;
    #pragma unroll
    for (int q = 0; q < 6; ++q) {
        const unsigned short* pp = part + (size_t)q * PLANE + e;
        unsigned u0 = *(const unsigned*)&pp[0];
        unsigned u1 = *(const unsigned*)&pp[2];
        a0 += __builtin_bit_cast(float, u0 << 16);
        a1 += __builtin_bit_cast(float, u0 & 0xffff0000u);
        a2 += __builtin_bit_cast(float, u1 << 16);
        a3 += __builtin_bit_cast(float, u1 & 0xffff0000u);
    }
    f32x4 v;
    v.x = a0 * (1.0f / 3.0f); v.y = a1 * (1.0f / 3.0f);
    v.z = a2 * (1.0f / 3.0f); v.w = a3 * (1.0f / 3.0f);
    *(f32x4*)&out[e] = v;
}

extern "C" void kernel_launch(void* const* d_in, const int* in_sizes, int n_in,
                              void* d_out, int out_size, void* d_ws, size_t ws_size,
                              hipStream_t stream)
{
    const float* x0 = (const float*)d_in[0];
    const float* x1 = (const float*)d_in[1];
    const float* x2 = (const float*)d_in[2];
    const float* w0 = (const float*)d_in[3];
    const float* w1 = (const float*)d_in[4];
    const float* w2 = (const float*)d_in[5];
    float* out = (float*)d_out;

    size_t nElem = (size_t)3 * BN * 64;
    unsigned short* Qbf = (unsigned short*)d_ws;
    unsigned short* Kbf = Qbf + nElem;
    unsigned short* Vt  = Kbf + nElem;
    unsigned short* part = Vt + nElem;      // 6 planes * BN*64 bf16

    hipLaunchKernelGGL(prep_kernel, dim3(3 * (BN / 128)), dim3(256), 0, stream,
                       x0, x1, x2, w0, w1, w2, Qbf, Kbf, Vt);
    hipLaunchKernelGGL(attn_kernel, dim3(6 * B_DIM * (N_DIM / 256)), dim3(256), 0, stream,
                       Qbf, Kbf, Vt, part);
    hipLaunchKernelGGL(reduce_kernel, dim3((BN * 64 / 4) / 256), dim3(256), 0, stream,
                       part, out);
}

// Round 7
// 212.803 us; speedup vs baseline: 1.7726x; 1.7726x over previous
//
#include <hip/hip_runtime.h>
#include <cstdint>
#include <cstddef>

#define B_DIM 16
#define N_DIM 2048
#define BN (B_DIM * N_DIM)          // 32768 rows per modality
#define QSCALE 0.18033688f          // 0.125 * log2(e): P = exp2(S')
#define PLANE ((size_t)BN * 64)     // elems per (jj,i) partial plane

typedef __attribute__((ext_vector_type(4))) float f32x4;
typedef __attribute__((ext_vector_type(16))) float f32x16;
typedef __attribute__((ext_vector_type(8))) __bf16 bf16x8;
typedef __attribute__((ext_vector_type(2))) unsigned int u32x2;

__device__ __forceinline__ unsigned short f2bf_rne(float f) {
    union { float f; unsigned int u; } v; v.f = f;
    unsigned int u = v.u;
    return (unsigned short)((u + 0x7fffu + ((u >> 16) & 1u)) >> 16);
}
__device__ __forceinline__ unsigned pk_rne(float a, float b) {
    return (unsigned)f2bf_rne(a) | ((unsigned)f2bf_rne(b) << 16);
}
// half_swap(a,b): res.x = {a.lo32, b.lo32}, res.y = {a.hi32, b.hi32}
__device__ __forceinline__ u32x2 half_swap(unsigned a, unsigned b) {
#if __has_builtin(__builtin_amdgcn_permlane32_swap)
    return __builtin_amdgcn_permlane32_swap(a, b, false, false);
#else
    unsigned pa = (unsigned)__shfl_xor((int)a, 32);
    unsigned pb = (unsigned)__shfl_xor((int)b, 32);
    bool hi = (threadIdx.x & 32) != 0;
    u32x2 r;
    r.x = hi ? pb : a;
    r.y = hi ? b : pa;
    return r;
#endif
}

// async global->LDS, 16B per lane; LDS dest = wave-uniform base + lane*16
__device__ __forceinline__ void g2lds16(const unsigned short* g, unsigned short* ldsbase) {
#if __has_builtin(__builtin_amdgcn_global_load_lds)
    __builtin_amdgcn_global_load_lds(
        (const __attribute__((address_space(1))) unsigned int*)g,
        (__attribute__((address_space(3))) unsigned int*)ldsbase,
        16, 0, 0);
#else
    int ln = threadIdx.x & 63;
    *(uint4*)(ldsbase + ln * 8) = *(const uint4*)g;
#endif
}

// ---------------------------------------------------------------------------
// prep (MFMA): Q = (x@W)*QSCALE, K = x@W^T  (bf16 rows), Vt = x^T (bf16, [m][b][d][n])
// (unchanged, verified)
// ---------------------------------------------------------------------------
__global__ __launch_bounds__(256) void prep_kernel(
    const float* __restrict__ x0, const float* __restrict__ x1, const float* __restrict__ x2,
    const float* __restrict__ w0, const float* __restrict__ w1, const float* __restrict__ w2,
    unsigned short* __restrict__ Qbf, unsigned short* __restrict__ Kbf,
    unsigned short* __restrict__ Vt)
{
    __shared__ float Wf[64 * 64];
    __shared__ float xs[128 * 68];

    int m    = blockIdx.x >> 8;
    int tile = blockIdx.x & 255;
    int row0 = tile * 128;
    int b    = row0 >> 11;
    int n0   = row0 & 2047;
    const float* x = (m == 0) ? x0 : (m == 1) ? x1 : x2;
    const float* W = (m == 0) ? w0 : (m == 1) ? w1 : w2;
    int tid = threadIdx.x;

    #pragma unroll
    for (int v = 0; v < 4; ++v) {
        int i4 = v * 256 + tid;
        *(f32x4*)&Wf[i4 * 4] = *(const f32x4*)&W[i4 * 4];
    }
    #pragma unroll
    for (int v = 0; v < 8; ++v) {
        int i4 = v * 256 + tid;
        int r = i4 >> 4, c = (i4 & 15) * 4;
        *(f32x4*)&xs[r * 68 + c] = *(const f32x4*)&x[(size_t)row0 * 64 + i4 * 4];
    }
    __syncthreads();

    int lane = tid & 63, wave = tid >> 6, lq = lane & 31, h = lane >> 5;

    bf16x8 wq[2][4], wk[2][4];
    #pragma unroll
    for (int mf = 0; mf < 2; ++mf)
        #pragma unroll
        for (int kc = 0; kc < 4; ++kc) {
            int e  = mf * 32 + lq;
            int d0 = kc * 16 + h * 8;
            unsigned uq[4], uk[4];
            #pragma unroll
            for (int t = 0; t < 4; ++t) {
                int d = d0 + 2 * t;
                uq[t] = pk_rne(Wf[d * 64 + e] * QSCALE, Wf[(d + 1) * 64 + e] * QSCALE);
                uk[t] = pk_rne(Wf[e * 64 + d], Wf[e * 64 + d + 1]);
            }
            uint4 ua; ua.x = uq[0]; ua.y = uq[1]; ua.z = uq[2]; ua.w = uq[3];
            uint4 ub; ub.x = uk[0]; ub.y = uk[1]; ub.z = uk[2]; ub.w = uk[3];
            wq[mf][kc] = __builtin_bit_cast(bf16x8, ua);
            wk[mf][kc] = __builtin_bit_cast(bf16x8, ub);
        }

    bf16x8 xb[4];
    #pragma unroll
    for (int kc = 0; kc < 4; ++kc) {
        const float* xr = &xs[(wave * 32 + lq) * 68 + kc * 16 + h * 8];
        unsigned u[4];
        #pragma unroll
        for (int t = 0; t < 4; ++t) u[t] = pk_rne(xr[2 * t], xr[2 * t + 1]);
        uint4 ua; ua.x = u[0]; ua.y = u[1]; ua.z = u[2]; ua.w = u[3];
        xb[kc] = __builtin_bit_cast(bf16x8, ua);
    }

    f32x16 Qt[2], Kt[2];
    #pragma unroll
    for (int r = 0; r < 16; ++r) { Qt[0][r] = 0.f; Qt[1][r] = 0.f; Kt[0][r] = 0.f; Kt[1][r] = 0.f; }
    #pragma unroll
    for (int kc = 0; kc < 4; ++kc) {
        #pragma unroll
        for (int mf = 0; mf < 2; ++mf) {
            Qt[mf] = __builtin_amdgcn_mfma_f32_32x32x16_bf16(wq[mf][kc], xb[kc], Qt[mf], 0, 0, 0);
            Kt[mf] = __builtin_amdgcn_mfma_f32_32x32x16_bf16(wk[mf][kc], xb[kc], Kt[mf], 0, 0, 0);
        }
    }

    size_t rowidx = (size_t)m * BN + row0 + wave * 32 + lq;
    unsigned short* qdst = Qbf + rowidx * 64 + h * 32;
    unsigned short* kdst = Kbf + rowidx * 64 + h * 32;
    #pragma unroll
    for (int s = 0; s < 4; ++s) {
        unsigned q00 = pk_rne(Qt[0][4 * s], Qt[0][4 * s + 1]);
        unsigned q01 = pk_rne(Qt[0][4 * s + 2], Qt[0][4 * s + 3]);
        unsigned q10 = pk_rne(Qt[1][4 * s], Qt[1][4 * s + 1]);
        unsigned q11 = pk_rne(Qt[1][4 * s + 2], Qt[1][4 * s + 3]);
        u32x2 a = half_swap(q00, q10);
        u32x2 c = half_swap(q01, q11);
        uint4 w; w.x = a.x; w.y = c.x; w.z = a.y; w.w = c.y;
        *(uint4*)&qdst[s * 8] = w;

        unsigned k00 = pk_rne(Kt[0][4 * s], Kt[0][4 * s + 1]);
        unsigned k01 = pk_rne(Kt[0][4 * s + 2], Kt[0][4 * s + 3]);
        unsigned k10 = pk_rne(Kt[1][4 * s], Kt[1][4 * s + 1]);
        unsigned k11 = pk_rne(Kt[1][4 * s + 2], Kt[1][4 * s + 3]);
        u32x2 a2 = half_swap(k00, k10);
        u32x2 c2 = half_swap(k01, k11);
        uint4 w2; w2.x = a2.x; w2.y = c2.x; w2.z = a2.y; w2.w = c2.y;
        *(uint4*)&kdst[s * 8] = w2;
    }

    int d  = tid & 63;
    int ng = tid >> 6;
    unsigned short* vdst = Vt + ((size_t)(m * B_DIM + b) * 64 + d) * 2048 + n0 + ng * 32;
    #pragma unroll
    for (int s = 0; s < 4; ++s) {
        uint4 w;
        w.x = pk_rne(xs[(ng * 32 + 8 * s + 0) * 68 + d], xs[(ng * 32 + 8 * s + 1) * 68 + d]);
        w.y = pk_rne(xs[(ng * 32 + 8 * s + 2) * 68 + d], xs[(ng * 32 + 8 * s + 3) * 68 + d]);
        w.z = pk_rne(xs[(ng * 32 + 8 * s + 4) * 68 + d], xs[(ng * 32 + 8 * s + 5) * 68 + d]);
        w.w = pk_rne(xs[(ng * 32 + 8 * s + 6) * 68 + d], xs[(ng * 32 + 8 * s + 7) * 68 + d]);
        *(uint4*)&vdst[s * 8] = w;
    }
}

// ---------------------------------------------------------------------------
// attention: block = one (pair, b, 256-q tile); 4 waves x 64 q-rows each.
// Quad-buffered LDS (DMA one tile ahead, one barrier per tile) with a
// kf-granularity software pipeline: exp/pack(g-1) -> QK(g) -> PV(g-1).
// MFMA work is adjacent to VALU/trans work with no dependency -> pipes overlap.
// ---------------------------------------------------------------------------
__global__ __launch_bounds__(256, 2) void attn_kernel(
    const unsigned short* __restrict__ Qbf,
    const unsigned short* __restrict__ Kbf,
    const unsigned short* __restrict__ Vt,
    unsigned short* __restrict__ part)
{
    __shared__ unsigned short Ks[4][4096];   // [key][d], XOR-chunk swizzled
    __shared__ unsigned short Vs[4][4096];   // [d][key], XOR-chunk swizzled

    int blk = blockIdx.x;                    // 768 = 6 pairs * 16 b * 8 qt
    int qt  = blk & 7;
    int b   = (blk >> 3) & 15;
    int p   = blk >> 7;
    int i   = p >> 1, jj = p & 1;
    int j   = i + 1 + jj; if (j >= 3) j -= 3;
    int q0  = qt * 256;

    int tid = threadIdx.x, wave = tid >> 6, lane = tid & 63;
    int lq = lane & 31, h = lane >> 5;

    const unsigned short* Kg = Kbf + ((size_t)j * BN + b * N_DIM) * 64;
    const unsigned short* Vg = Vt + (size_t)(j * B_DIM + b) * 64 * 2048;

    // staging geometry (verified in R5): swizzle on global side
    int rK   = wave * 16 + (lane >> 3);
    int sw8  = ((lane & 7) ^ ((lane >> 3) & 7)) * 8;
    size_t gkOff0 = (size_t)rK * 64 + sw8;
    size_t gkOff1 = (size_t)(rK + 8) * 64 + sw8;
    size_t gvOff0 = (size_t)rK * 2048 + sw8;
    size_t gvOff1 = (size_t)(rK + 8) * 2048 + sw8;

    auto stage = [&](int buf, int kt) {
        const unsigned short* gk = Kg + (size_t)kt * 4096;
        const unsigned short* gv = Vg + kt * 64;
        g2lds16(gk + gkOff0, &Ks[buf][wave * 1024]);
        g2lds16(gk + gkOff1, &Ks[buf][wave * 1024 + 512]);
        g2lds16(gv + gvOff0, &Vs[buf][wave * 1024]);
        g2lds16(gv + gvOff1, &Vs[buf][wave * 1024 + 512]);
    };

    // prologue: stage tiles 0 and 1
    stage(0, 0);
    stage(1, 1);

    // Q B-frags (block-constant)
    const unsigned short* Qg = Qbf + ((size_t)i * BN + b * N_DIM + q0 + wave * 64) * 64;
    bf16x8 qf[2][4];
    #pragma unroll
    for (int qi = 0; qi < 2; ++qi)
        #pragma unroll
        for (int kc = 0; kc < 4; ++kc)
            qf[qi][kc] = __builtin_bit_cast(bf16x8,
                *(const uint4*)&Qg[(qi * 32 + lq) * 64 + kc * 16 + h * 8]);

    f32x16 O[2][2];                          // [df][qi]
    #pragma unroll
    for (int r = 0; r < 16; ++r) { O[0][0][r] = 0.f; O[0][1][r] = 0.f; O[1][0][r] = 0.f; O[1][1][r] = 0.f; }
    float lsum[2] = {0.f, 0.f};

    __syncthreads();    // publishes tiles 0,1 (drains this wave's DMA; all waves sync)

    // pipeline prime: QK of stage g=0 (tile 0, kf 0)
    f32x16 st[2];
    {
        const unsigned short* Kb = Ks[0];
        int key = lq;
        bf16x8 kfr[4];
        #pragma unroll
        for (int kc = 0; kc < 4; ++kc)
            kfr[kc] = __builtin_bit_cast(bf16x8,
                *(const uint4*)&Kb[key * 64 + (((2 * kc + h) ^ (key & 7)) * 8)]);
        #pragma unroll
        for (int qi = 0; qi < 2; ++qi) {
            f32x16 acc;
            #pragma unroll
            for (int r = 0; r < 16; ++r) acc[r] = 0.f;
            #pragma unroll
            for (int kc = 0; kc < 4; ++kc)
                acc = __builtin_amdgcn_mfma_f32_32x32x16_bf16(kfr[kc], qf[qi][kc], acc, 0, 0, 0);
            st[qi] = acc;
        }
    }

    for (int g = 1; g < 64; ++g) {
        int kt = g >> 1, kf = g & 1;
        if (kf == 0) {
            __syncthreads();                        // one barrier per tile
            if (kt < 31) stage((kt + 1) & 3, kt + 1);
        }

        // ---- exp/pack of stage g-1 (scores ready since last iteration) ----
        unsigned pkk[2][4][2];
        #pragma unroll
        for (int qi = 0; qi < 2; ++qi)
            #pragma unroll
            for (int s = 0; s < 4; ++s) {
                float e0 = __builtin_amdgcn_exp2f(st[qi][4 * s + 0]);
                float e1 = __builtin_amdgcn_exp2f(st[qi][4 * s + 1]);
                float e2 = __builtin_amdgcn_exp2f(st[qi][4 * s + 2]);
                float e3 = __builtin_amdgcn_exp2f(st[qi][4 * s + 3]);
                lsum[qi] += (e0 + e1) + (e2 + e3);
                pkk[qi][s][0] = __builtin_amdgcn_perm(
                    __builtin_bit_cast(unsigned, e1), __builtin_bit_cast(unsigned, e0), 0x07060302u);
                pkk[qi][s][1] = __builtin_amdgcn_perm(
                    __builtin_bit_cast(unsigned, e3), __builtin_bit_cast(unsigned, e2), 0x07060302u);
            }

        // ---- QK of stage g (independent of the exp above) ----
        {
            const unsigned short* Kb = Ks[kt & 3];
            int key = kf * 32 + lq;
            bf16x8 kfr[4];
            #pragma unroll
            for (int kc = 0; kc < 4; ++kc)
                kfr[kc] = __builtin_bit_cast(bf16x8,
                    *(const uint4*)&Kb[key * 64 + (((2 * kc + h) ^ (key & 7)) * 8)]);
            #pragma unroll
            for (int qi = 0; qi < 2; ++qi) {
                f32x16 acc;
                #pragma unroll
                for (int r = 0; r < 16; ++r) acc[r] = 0.f;
                #pragma unroll
                for (int kc = 0; kc < 4; ++kc)
                    acc = __builtin_amdgcn_mfma_f32_32x32x16_bf16(kfr[kc], qf[qi][kc], acc, 0, 0, 0);
                st[qi] = acc;
            }
        }

        // ---- PV of stage g-1 ----
        {
            int gp = g - 1, kfp = gp & 1;
            const unsigned short* Vb = Vs[(gp >> 1) & 3];
            #pragma unroll
            for (int c = 0; c < 2; ++c) {
                bf16x8 pf[2];
                #pragma unroll
                for (int qi = 0; qi < 2; ++qi) {
                    u32x2 rr0 = half_swap(pkk[qi][2 * c][0], pkk[qi][2 * c + 1][0]);
                    u32x2 rr1 = half_swap(pkk[qi][2 * c][1], pkk[qi][2 * c + 1][1]);
                    uint4 t; t.x = rr0.x; t.y = rr1.x; t.z = rr0.y; t.w = rr1.y;
                    pf[qi] = __builtin_bit_cast(bf16x8, t);
                }
                int kcpv = 2 * kfp + c;
                #pragma unroll
                for (int df = 0; df < 2; ++df) {
                    int d = df * 32 + lq;
                    bf16x8 vfr = __builtin_bit_cast(bf16x8,
                        *(const uint4*)&Vb[d * 64 + (((2 * kcpv + h) ^ (d & 7)) * 8)]);
                    O[df][0] = __builtin_amdgcn_mfma_f32_32x32x16_bf16(vfr, pf[0], O[df][0], 0, 0, 0);
                    O[df][1] = __builtin_amdgcn_mfma_f32_32x32x16_bf16(vfr, pf[1], O[df][1], 0, 0, 0);
                }
            }
        }
    }

    // ---- drain: exp/pack + PV of last stage (g = 63: tile 31, kf 1) ----
    {
        unsigned pkk[2][4][2];
        #pragma unroll
        for (int qi = 0; qi < 2; ++qi)
            #pragma unroll
            for (int s = 0; s < 4; ++s) {
                float e0 = __builtin_amdgcn_exp2f(st[qi][4 * s + 0]);
                float e1 = __builtin_amdgcn_exp2f(st[qi][4 * s + 1]);
                float e2 = __builtin_amdgcn_exp2f(st[qi][4 * s + 2]);
                float e3 = __builtin_amdgcn_exp2f(st[qi][4 * s + 3]);
                lsum[qi] += (e0 + e1) + (e2 + e3);
                pkk[qi][s][0] = __builtin_amdgcn_perm(
                    __builtin_bit_cast(unsigned, e1), __builtin_bit_cast(unsigned, e0), 0x07060302u);
                pkk[qi][s][1] = __builtin_amdgcn_perm(
                    __builtin_bit_cast(unsigned, e3), __builtin_bit_cast(unsigned, e2), 0x07060302u);
            }
        const unsigned short* Vb = Vs[31 & 3];
        #pragma unroll
        for (int c = 0; c < 2; ++c) {
            bf16x8 pf[2];
            #pragma unroll
            for (int qi = 0; qi < 2; ++qi) {
                u32x2 rr0 = half_swap(pkk[qi][2 * c][0], pkk[qi][2 * c + 1][0]);
                u32x2 rr1 = half_swap(pkk[qi][2 * c][1], pkk[qi][2 * c + 1][1]);
                uint4 t; t.x = rr0.x; t.y = rr1.x; t.z = rr0.y; t.w = rr1.y;
                pf[qi] = __builtin_bit_cast(bf16x8, t);
            }
            int kcpv = 2 * 1 + c;
            #pragma unroll
            for (int df = 0; df < 2; ++df) {
                int d = df * 32 + lq;
                bf16x8 vfr = __builtin_bit_cast(bf16x8,
                    *(const uint4*)&Vb[d * 64 + (((2 * kcpv + h) ^ (d & 7)) * 8)]);
                O[df][0] = __builtin_amdgcn_mfma_f32_32x32x16_bf16(vfr, pf[0], O[df][0], 0, 0, 0);
                O[df][1] = __builtin_amdgcn_mfma_f32_32x32x16_bf16(vfr, pf[1], O[df][1], 0, 0, 0);
            }
        }
    }

    // epilogue: normalize, half-swap to row layout, store bf16 partial rows
    #pragma unroll
    for (int qi = 0; qi < 2; ++qi) {
        float l = lsum[qi];
        l += __shfl_xor(l, 32);
        float inv = 1.0f / l;
        #pragma unroll
        for (int r = 0; r < 16; ++r) { O[0][qi][r] *= inv; O[1][qi][r] *= inv; }

        unsigned short* dst = part + ((size_t)jj * 3 + i) * PLANE
            + (size_t)(b * N_DIM + q0 + wave * 64 + qi * 32 + lq) * 64 + h * 32;
        #pragma unroll
        for (int s = 0; s < 4; ++s) {
            unsigned t00 = pk_rne(O[0][qi][4 * s], O[0][qi][4 * s + 1]);
            unsigned t01 = pk_rne(O[0][qi][4 * s + 2], O[0][qi][4 * s + 3]);
            unsigned t10 = pk_rne(O[1][qi][4 * s], O[1][qi][4 * s + 1]);
            unsigned t11 = pk_rne(O[1][qi][4 * s + 2], O[1][qi][4 * s + 3]);
            u32x2 a = half_swap(t00, t10);
            u32x2 c = half_swap(t01, t11);
            uint4 w; w.x = a.x; w.y = c.x; w.z = a.y; w.w = c.y;
            *(uint4*)&dst[s * 8] = w;
        }
    }
}

// ---------------------------------------------------------------------------
// reduce: out = (1/3) * sum of 6 bf16 partial planes
// ---------------------------------------------------------------------------
__global__ __launch_bounds__(256) void reduce_kernel(
    const unsigned short* __restrict__ part, float* __restrict__ out)
{
    size_t e = ((size_t)blockIdx.x * 256 + threadIdx.x) * 4;
    float a0 = 0.f, a1 = 0.f, a2 = 0.f, a3 = 0.f;
    #pragma unroll
    for (int q = 0; q < 6; ++q) {
        const unsigned short* pp = part + (size_t)q * PLANE + e;
        unsigned u0 = *(const unsigned*)&pp[0];
        unsigned u1 = *(const unsigned*)&pp[2];
        a0 += __builtin_bit_cast(float, u0 << 16);
        a1 += __builtin_bit_cast(float, u0 & 0xffff0000u);
        a2 += __builtin_bit_cast(float, u1 << 16);
        a3 += __builtin_bit_cast(float, u1 & 0xffff0000u);
    }
    f32x4 v;
    v.x = a0 * (1.0f / 3.0f); v.y = a1 * (1.0f / 3.0f);
    v.z = a2 * (1.0f / 3.0f); v.w = a3 * (1.0f / 3.0f);
    *(f32x4*)&out[e] = v;
}

extern "C" void kernel_launch(void* const* d_in, const int* in_sizes, int n_in,
                              void* d_out, int out_size, void* d_ws, size_t ws_size,
                              hipStream_t stream)
{
    const float* x0 = (const float*)d_in[0];
    const float* x1 = (const float*)d_in[1];
    const float* x2 = (const float*)d_in[2];
    const float* w0 = (const float*)d_in[3];
    const float* w1 = (const float*)d_in[4];
    const float* w2 = (const float*)d_in[5];
    float* out = (float*)d_out;

    size_t nElem = (size_t)3 * BN * 64;
    unsigned short* Qbf = (unsigned short*)d_ws;
    unsigned short* Kbf = Qbf + nElem;
    unsigned short* Vt  = Kbf + nElem;
    unsigned short* part = Vt + nElem;      // 6 planes * BN*64 bf16

    hipLaunchKernelGGL(prep_kernel, dim3(3 * (BN / 128)), dim3(256), 0, stream,
                       x0, x1, x2, w0, w1, w2, Qbf, Kbf, Vt);
    hipLaunchKernelGGL(attn_kernel, dim3(6 * B_DIM * (N_DIM / 256)), dim3(256), 0, stream,
                       Qbf, Kbf, Vt, part);
    hipLaunchKernelGGL(reduce_kernel, dim3((BN * 64 / 4) / 256), dim3(256), 0, stream,
                       part, out);
}